// Round 5
// baseline (899.987 us; speedup 1.0000x reference)
//
#include <hip/hip_runtime.h>
#include <hip/hip_bf16.h>
#include <stdint.h>

#define N_BATCH 4096
#define HID     1024
#define OBSLEN  20

#define BM  256   // batch rows per block
#define BK  64    // K per stage
// Block owns 256 output cols = 64 hcols x 4 gates (gate-interleaved, see prep).
// Output matrix: [4096 rows][4096 cols] -> grid (16,16), 512 thr = 8 waves.

using short8 = __attribute__((ext_vector_type(8))) short;
using f32x4  = __attribute__((ext_vector_type(4))) float;

#define AS1 __attribute__((address_space(1)))
#define AS3 __attribute__((address_space(3)))

__device__ __forceinline__ float rcpf(float x) { return __builtin_amdgcn_rcpf(x); }
__device__ __forceinline__ float sigf(float x) { return rcpf(1.f + __expf(-x)); }
__device__ __forceinline__ float tanh_(float x) {
    float a = fminf(15.f, fmaxf(-15.f, x));
    float t = __expf(-2.f * a);
    return (1.f - t) * rcpf(1.f + t);
}
__device__ __forceinline__ unsigned short f2bf(float f) {
    __hip_bfloat16 b = __float2bfloat16(f);
    return *reinterpret_cast<unsigned short*>(&b);
}
__device__ __forceinline__ float bf2f(unsigned short u) {
    unsigned int x = ((unsigned int)u) << 16;
    return __uint_as_float(x);
}

// ---------------------------------------------------------------- prep ----
// hA = bf16(h0); cst = 0; Wg = bf16(W_hh) gate-interleaved row permutation:
// dest row R = by*256 + c' (by in [0,16)): gate g=(c'>>4)&3,
// hcol_local=((c'>>6)<<4)|(c'&15); source row = g*1024 + by*64 + hcol_local.
__global__ __launch_bounds__(256) void prep_kernel(
    const float4* __restrict__ Whh, const float4* __restrict__ h0,
    ushort4* __restrict__ Wg, ushort4* __restrict__ hb, float4* __restrict__ c, int n4)
{
    int i = blockIdx.x * 256 + threadIdx.x;
    if (i < n4) {
        float4 h = h0[i];
        hb[i] = make_ushort4(f2bf(h.x), f2bf(h.y), f2bf(h.z), f2bf(h.w));
        c[i] = make_float4(0.f, 0.f, 0.f, 0.f);
        int R  = i >> 8, k4 = i & 255;
        int by = R >> 8, cp = R & 255;
        int g  = (cp >> 4) & 3;
        int hl = ((cp >> 6) << 4) | (cp & 15);
        int orig = g * HID + by * 64 + hl;
        float4 w = Whh[orig * 256 + k4];
        Wg[i] = make_ushort4(f2bf(w.x), f2bf(w.y), f2bf(w.z), f2bf(w.w));
    }
}

// ---------------------------------------------------------- lstm step ----
// 8-phase m201-style schedule, 2 K-tiles per iteration, 16 MFMA/phase.
// LDS 128KB: A[2 slots][256][64]bf16 @0, B[2 slots][256][64]bf16 @65536.
// Content swizzle: element (row,kbyte) at row*128 + (kbyte ^ ((row&7)<<4)).
// Halves: A by f-frag (H0 = rows {0-63,128-191}, H1 = {64-127,192-255});
//         B by n-frag (G0 = rows {0-31,64-95,...}, G1 = {32-63,96-127,...}).
// Stage 1 half (2 global_load_lds/thread) per phase; stage->read distance
// always 4-6 phases. vmcnt(6) end-ph1/ph5, vmcnt(8) end-ph4/ph8 (steady).
__global__ __launch_bounds__(512, 2) void lstm_step_kernel(
    const ushort* __restrict__ hin,   // [4096][1024] bf16 canonical
    const ushort* __restrict__ Wg,    // [4096][1024] bf16 permuted rows
    const float*  __restrict__ xt,    // [4096][2]
    const float*  __restrict__ Wih,   // [4096][2]
    const float*  __restrict__ bih,
    const float*  __restrict__ bhh,
    float*        __restrict__ cst,   // per-block [f][tid] float4 layout
    ushort*       __restrict__ hout)  // [4096][1024] bf16 canonical
{
    __shared__ __align__(16) char lds[131072];
    const int tid  = threadIdx.x;
    const int lane = tid & 63, l15 = lane & 15, l4 = lane >> 4;
    const int wid  = tid >> 6, wr = wid >> 2, wc = wid & 3;
    const int m0   = blockIdx.x * BM;
    const int by   = blockIdx.y;
    const int bid  = blockIdx.y * (N_BATCH / BM) + blockIdx.x;

    // ---- staging geometry (16B/thread/load; one round = 64 rows = 8KB) ----
    const int rowS = tid >> 3;                                  // 0..63
    const int offS = ((tid & 7) * 16) ^ ((rowS & 7) << 4);      // inverse-swizzled src byte
    const ushort* aS  = hin + (size_t)(m0 + rowS) * HID + (offS >> 1);
    // B rounds cover rows rowS + (rowS&32) + g*32 + r*128 (g-half striping)
    const ushort* bS2 = Wg + (size_t)(by * 256 + rowS + (rowS & 32)) * HID + (offS >> 1);
    char* aDb = lds + tid * 16;
    char* bDb = lds + 65536 + tid * 16 + (rowS & 32) * 128;

    auto stA = [&](int s, int k0, int h, int r) {
        __builtin_amdgcn_global_load_lds(
            (const AS1 void*)(aS + k0 + (size_t)(h * 64 + r * 128) * HID),
            (AS3 void*)(aDb + s * 32768 + (h * 64 + r * 128) * 128), 16, 0, 0);
    };
    auto stB = [&](int s, int k0, int g, int r) {
        __builtin_amdgcn_global_load_lds(
            (const AS1 void*)(bS2 + k0 + (size_t)(g * 32 + r * 128) * HID),
            (AS3 void*)(bDb + s * 32768 + (g * 32 + r * 128) * 128), 16, 0, 0);
    };

    // ---- ds_read per-lane offsets (byte offsets from lds base) ----
    const int swz = (l15 & 7) << 4;
    const int kb0 = (l4 * 16) ^ swz;                     // kk1 via ^64 (XOR commutes)
    const int aRd = (wr * 128 + l15) * 128 + kb0;        // + s*32768 + f*2048
    const int bRd = 65536 + (wc * 64 + l15) * 128 + kb0; // + s*32768 + n*2048

    f32x4 acc[8][4];
#pragma unroll
    for (int f = 0; f < 8; ++f)
#pragma unroll
        for (int n = 0; n < 4; ++n)
            acc[f][n] = (f32x4){0.f, 0.f, 0.f, 0.f};

    short8 af0[4], af1[4], bf0_[2], bf1_[2];

#define VM8 asm volatile("s_waitcnt vmcnt(8)" ::: "memory")
#define VM6 asm volatile("s_waitcnt vmcnt(6)" ::: "memory")
#define VM4 asm volatile("s_waitcnt vmcnt(4)" ::: "memory")
#define VM0 asm volatile("s_waitcnt vmcnt(0)" ::: "memory")
#define NOPW ((void)0)

#define PHASE(S, FH, NH, DO_A, STAGE_STMT, END_WAIT)                               \
    {                                                                              \
        if (DO_A) {                                                                \
            _Pragma("unroll") for (int f = 0; f < 4; ++f) {                        \
                const int o = aRd + (S) * 32768 + ((FH) * 4 + f) * 2048;           \
                af0[f] = *(const short8*)(lds + o);                                \
                af1[f] = *(const short8*)(lds + (o ^ 64));                         \
            }                                                                      \
        }                                                                          \
        _Pragma("unroll") for (int n = 0; n < 2; ++n) {                            \
            const int o = bRd + (S) * 32768 + ((NH) * 2 + n) * 2048;               \
            bf0_[n] = *(const short8*)(lds + o);                                   \
            bf1_[n] = *(const short8*)(lds + (o ^ 64));                            \
        }                                                                          \
        STAGE_STMT;                                                                \
        __builtin_amdgcn_s_barrier();                                              \
        asm volatile("s_waitcnt lgkmcnt(0)" ::: "memory");                         \
        __builtin_amdgcn_sched_barrier(0);                                         \
        __builtin_amdgcn_s_setprio(1);                                             \
        _Pragma("unroll") for (int f = 0; f < 4; ++f)                              \
            _Pragma("unroll") for (int n = 0; n < 2; ++n) {                        \
                acc[(FH)*4+f][(NH)*2+n] = __builtin_amdgcn_mfma_f32_16x16x32_bf16( \
                    af0[f], bf0_[n], acc[(FH)*4+f][(NH)*2+n], 0, 0, 0);            \
                acc[(FH)*4+f][(NH)*2+n] = __builtin_amdgcn_mfma_f32_16x16x32_bf16( \
                    af1[f], bf1_[n], acc[(FH)*4+f][(NH)*2+n], 0, 0, 0);            \
            }                                                                      \
        __builtin_amdgcn_s_setprio(0);                                             \
        END_WAIT;                                                                  \
        __builtin_amdgcn_sched_barrier(0);                                         \
        __builtin_amdgcn_s_barrier();                                              \
    }

    // ---- prologue: T0 fully + T1 H0/G0 (12 loads), oldest-first order ----
    stA(0, 0, 0, 0);  stA(0, 0, 0, 1);    // A-s0-H0
    stB(0, 0, 0, 0);  stB(0, 0, 0, 1);    // B-s0-G0
    stA(0, 0, 1, 0);  stA(0, 0, 1, 1);    // A-s0-H1
    stB(0, 0, 1, 0);  stB(0, 0, 1, 1);    // B-s0-G1
    stA(1, 64, 0, 0); stA(1, 64, 0, 1);   // A-s1-H0 (tile 1)
    stB(1, 64, 0, 0); stB(1, 64, 0, 1);   // B-s1-G0 (tile 1)
    VM8;                                   // land A-s0-H0, B-s0-G0
    __builtin_amdgcn_s_barrier();

    // ---- main loop: 7 full iterations (tiles 0..13), then peeled last ----
    for (int i = 0; i < 7; ++i) {
        const int kb1 = (2 * i + 1) * 64;
        const int kn0 = (2 * i + 2) * 64;
        const int kn1 = (2 * i + 3) * 64;
        PHASE(0, 0, 0, 1, (stA(1, kb1, 1, 0), stA(1, kb1, 1, 1)), VM6);
        PHASE(0, 0, 1, 0, (stB(1, kb1, 1, 0), stB(1, kb1, 1, 1)), NOPW);
        PHASE(0, 1, 0, 1, (stA(0, kn0, 0, 0), stA(0, kn0, 0, 1)), NOPW);
        PHASE(0, 1, 1, 0, (stB(0, kn0, 0, 0), stB(0, kn0, 0, 1)), VM8);
        PHASE(1, 0, 0, 1, (stA(0, kn0, 1, 0), stA(0, kn0, 1, 1)), VM6);
        PHASE(1, 0, 1, 0, (stB(0, kn0, 1, 0), stB(0, kn0, 1, 1)), NOPW);
        PHASE(1, 1, 0, 1, (stA(1, kn1, 0, 0), stA(1, kn1, 0, 1)), NOPW);
        PHASE(1, 1, 1, 0, (stB(1, kn1, 0, 0), stB(1, kn1, 0, 1)), VM8);
    }
    {   // last iteration: tiles 14,15; no next-iter staging
        const int kb1 = 15 * 64;
        PHASE(0, 0, 0, 1, (stA(1, kb1, 1, 0), stA(1, kb1, 1, 1)), VM6);
        PHASE(0, 0, 1, 0, (stB(1, kb1, 1, 0), stB(1, kb1, 1, 1)), NOPW);
        PHASE(0, 1, 0, 1, NOPW, NOPW);
        PHASE(0, 1, 1, 0, NOPW, VM4);     // land A-s1-H0, B-s1-G0 (staged prev iter)
        PHASE(1, 0, 0, 1, NOPW, VM0);     // land ph1/ph2 stages (A-s1-H1, B-s1-G1)
        PHASE(1, 0, 1, 0, NOPW, NOPW);
        PHASE(1, 1, 0, 1, NOPW, NOPW);
        PHASE(1, 1, 1, 0, NOPW, NOPW);
    }

    // ---------------- epilogue: fused LSTM pointwise update ----------------
    float4* c4 = (float4*)cst + (size_t)bid * 4096;   // [f][tid] float4
    float4 cv[8];
#pragma unroll
    for (int f = 0; f < 8; ++f) cv[f] = c4[f * 512 + tid];

    const int hcg = by * 64 + wc * 16 + l15;          // global h column
    float wi0[4], wi1[4], bs_[4];
#pragma unroll
    for (int n = 0; n < 4; ++n) {
        int j = n * HID + hcg;
        wi0[n] = Wih[j * 2 + 0];
        wi1[n] = Wih[j * 2 + 1];
        bs_[n] = bih[j] + bhh[j];
    }
    const float2* xt2 = (const float2*)xt;
#pragma unroll
    for (int f = 0; f < 8; ++f) {
#pragma unroll
        for (int r = 0; r < 4; ++r) {
            int nrow = m0 + wr * 128 + f * 16 + l4 * 4 + r;
            float2 x = xt2[nrow];
            float gi = acc[f][0][r] + x.x * wi0[0] + x.y * wi1[0] + bs_[0];
            float gf = acc[f][1][r] + x.x * wi0[1] + x.y * wi1[1] + bs_[1];
            float gg = acc[f][2][r] + x.x * wi0[2] + x.y * wi1[2] + bs_[2];
            float go = acc[f][3][r] + x.x * wi0[3] + x.y * wi1[3] + bs_[3];
            float iv = sigf(gi), fv = sigf(gf);
            float gv = tanh_(gg), ov = sigf(go);
            float cn = fv * cv[f][r] + iv * gv;
            cv[f][r] = cn;
            hout[(size_t)nrow * HID + hcg] = f2bf(ov * tanh_(cn));
        }
        c4[f * 512 + tid] = cv[f];
    }
#undef PHASE
#undef VM8
#undef VM6
#undef VM4
#undef VM0
#undef NOPW
}

// ----------------------------------------------------------- out proj ----
__global__ __launch_bounds__(256) void out_proj_kernel(
    const ushort* __restrict__ h, const float* __restrict__ Wout,
    const float* __restrict__ bout, float* __restrict__ outt)
{
    const int wid = threadIdx.x >> 6, lane = threadIdx.x & 63;
    const int row = blockIdx.x * 4 + wid;
    const ushort* hr = h + (size_t)row * HID + lane * 16;
    float a0 = 0.f, a1 = 0.f;
#pragma unroll
    for (int half = 0; half < 2; ++half) {
        short8 hv = *(const short8*)(hr + half * 8);
#pragma unroll
        for (int j = 0; j < 8; ++j) {
            int k = lane * 16 + half * 8 + j;
            float f = bf2f((unsigned short)hv[j]);
            a0 += f * Wout[k];
            a1 += f * Wout[HID + k];
        }
    }
#pragma unroll
    for (int off = 32; off > 0; off >>= 1) {
        a0 += __shfl_down(a0, off);
        a1 += __shfl_down(a1, off);
    }
    if (lane == 0) {
        outt[row * 2 + 0] = a0 + bout[0];
        outt[row * 2 + 1] = a1 + bout[1];
    }
}

// ------------------------------------------------------------- launch ----
extern "C" void kernel_launch(void* const* d_in, const int* in_sizes, int n_in,
                              void* d_out, int out_size, void* d_ws, size_t ws_size,
                              hipStream_t stream) {
    const float* obs  = (const float*)d_in[0];
    const float* h0   = (const float*)d_in[1];
    const float* Wih  = (const float*)d_in[2];
    const float* Whh  = (const float*)d_in[3];
    const float* bih  = (const float*)d_in[4];
    const float* bhh  = (const float*)d_in[5];
    const float* Wout = (const float*)d_in[6];
    const float* bout = (const float*)d_in[7];
    float* out = (float*)d_out;

    char* ws = (char*)d_ws;
    ushort* Wg = (ushort*)(ws);                 // 8 MB bf16 W_hh (permuted)
    ushort* hA = (ushort*)(ws + (8  << 20));    // 8 MB bf16 h ping
    ushort* hB = (ushort*)(ws + (16 << 20));    // 8 MB bf16 h pong
    float*  c  = (float* )(ws + (24 << 20));    // 16 MB fp32 c state (block-local)

    prep_kernel<<<4096, 256, 0, stream>>>((const float4*)Whh, (const float4*)h0,
                                          (ushort4*)Wg, (ushort4*)hA, (float4*)c,
                                          N_BATCH * HID / 4);

    ushort* hin = hA;
    ushort* hou = hB;
    for (int t = 0; t < OBSLEN; ++t) {
        const float* xt = obs + (size_t)(t == 0 ? 0 : (t - 1)) * N_BATCH * 2;
        lstm_step_kernel<<<dim3(N_BATCH / BM, (4 * HID) / 256), 512, 0, stream>>>(
            hin, Wg, xt, Wih, bih, bhh, c, hou);
        out_proj_kernel<<<N_BATCH / 4, 256, 0, stream>>>(
            hou, Wout, bout, out + (size_t)t * N_BATCH * 2);
        ushort* tmp = hin; hin = hou; hou = tmp;
    }
}

// Round 6
// 868.911 us; speedup vs baseline: 1.0358x; 1.0358x over previous
//
#include <hip/hip_runtime.h>
#include <hip/hip_bf16.h>
#include <stdint.h>

#define N_BATCH 4096
#define HID     1024
#define OBSLEN  20

#define BM  256   // batch rows per block
#define BK  64    // K per stage
// Block owns 256 output cols = 64 hcols x 4 gates (gate-interleaved, see prep).
// Output: [4096 rows][4096 cols] -> 256 blocks, XCD-swizzled internally.

using short8 = __attribute__((ext_vector_type(8))) short;
using f32x4  = __attribute__((ext_vector_type(4))) float;

#define AS1 __attribute__((address_space(1)))
#define AS3 __attribute__((address_space(3)))

__device__ __forceinline__ float rcpf(float x) { return __builtin_amdgcn_rcpf(x); }
__device__ __forceinline__ float sigf(float x) { return rcpf(1.f + __expf(-x)); }
__device__ __forceinline__ float tanh_(float x) {
    float a = fminf(15.f, fmaxf(-15.f, x));
    float t = __expf(-2.f * a);
    return (1.f - t) * rcpf(1.f + t);
}
__device__ __forceinline__ unsigned short f2bf(float f) {
    __hip_bfloat16 b = __float2bfloat16(f);
    return *reinterpret_cast<unsigned short*>(&b);
}
__device__ __forceinline__ float bf2f(unsigned short u) {
    unsigned int x = ((unsigned int)u) << 16;
    return __uint_as_float(x);
}

// ---------------------------------------------------------------- prep ----
// hA = bf16(h0); cst = 0; Wg = bf16(W_hh) gate-interleaved row permutation:
// dest row R = by*256 + c' (by in [0,16)): gate g=(c'>>4)&3,
// hcol_local=((c'>>6)<<4)|(c'&15); source row = g*1024 + by*64 + hcol_local.
__global__ __launch_bounds__(256) void prep_kernel(
    const float4* __restrict__ Whh, const float4* __restrict__ h0,
    ushort4* __restrict__ Wg, ushort4* __restrict__ hb, float4* __restrict__ c, int n4)
{
    int i = blockIdx.x * 256 + threadIdx.x;
    if (i < n4) {
        float4 h = h0[i];
        hb[i] = make_ushort4(f2bf(h.x), f2bf(h.y), f2bf(h.z), f2bf(h.w));
        c[i] = make_float4(0.f, 0.f, 0.f, 0.f);
        int R  = i >> 8, k4 = i & 255;
        int by = R >> 8, cp = R & 255;
        int g  = (cp >> 4) & 3;
        int hl = ((cp >> 6) << 4) | (cp & 15);
        int orig = g * HID + by * 64 + hl;
        float4 w = Whh[orig * 256 + k4];
        Wg[i] = make_ushort4(f2bf(w.x), f2bf(w.y), f2bf(w.z), f2bf(w.w));
    }
}

// ---------------------------------------------------------- lstm step ----
// Per-wave software pipeline: 4 MFMA groups of 16 per K-tile; each group
// issues next group's ds_reads then MFMAs on prev-read frags (compiler emits
// fine-grained lgkmcnt). ONE __syncthreads per tile (at end of g2) = the
// vmcnt(0)+lgkmcnt(0) drain for slot swap. Staging: B(kt+1) at g0 (2 groups
// before drain), A(kt+2) at g3 (3 groups; slot freed by the barrier).
// LDS 128KB: A[2][256][64]bf16 @0, B[2][256][64]bf16 @65536.
// Content swizzle: element (row,kbyte) at row*128 + (kbyte ^ ((row&7)<<4)).
__global__ __launch_bounds__(512, 2) void lstm_step_kernel(
    const ushort* __restrict__ hin,   // [4096][1024] bf16 canonical
    const ushort* __restrict__ Wg,    // [4096][1024] bf16 permuted rows
    const float*  __restrict__ xt,    // [4096][2]
    const float*  __restrict__ Wih,   // [4096][2]
    const float*  __restrict__ bih,
    const float*  __restrict__ bhh,
    float*        __restrict__ cst,   // per-block [f][tid] float4 layout
    ushort*       __restrict__ hout)  // [4096][1024] bf16 canonical
{
    __shared__ __align__(16) char lds[131072];
    const int tid  = threadIdx.x;
    const int lane = tid & 63, l15 = lane & 15, l4 = lane >> 4;
    const int wid  = tid >> 6, wr = wid >> 2, wc = wid & 3;

    // XCD-aware remap: dispatch-linear L runs on XCD L%8; give each XCD two
    // whole col-groups so its 1MB W slice stays L2-resident.
    const int L    = blockIdx.x + (int)gridDim.x * blockIdx.y;  // gridDim.x=16
    const int xcd  = L & 7, slot = L >> 3;                       // slot 0..31
    const int xb   = slot & 15;
    const int yb   = (xcd << 1) | (slot >> 4);
    const int m0   = xb * BM;
    const int by   = yb;
    const int bid  = yb * 16 + xb;                               // stable c-slice id

    // ---- staging geometry (16B/thread/load; one round = 64 rows = 8KB) ----
    const int rowS = tid >> 3;                                  // 0..63
    const int offS = ((tid & 7) * 16) ^ ((rowS & 7) << 4);      // inverse-swizzled src byte
    const ushort* aS = hin + (size_t)(m0 + rowS) * HID + (offS >> 1);
    const ushort* bS = Wg  + (size_t)(by * 256 + rowS) * HID + (offS >> 1);
    char* aD = lds + tid * 16;
    char* bD = lds + 65536 + tid * 16;

    auto stA = [&](int s, int k0, int r) {
        __builtin_amdgcn_global_load_lds(
            (const AS1 void*)(aS + k0 + (size_t)r * 64 * HID),
            (AS3 void*)(aD + s * 32768 + r * 8192), 16, 0, 0);
    };
    auto stB = [&](int s, int k0, int r) {
        __builtin_amdgcn_global_load_lds(
            (const AS1 void*)(bS + k0 + (size_t)r * 64 * HID),
            (AS3 void*)(bD + s * 32768 + r * 8192), 16, 0, 0);
    };

    // ---- ds_read per-lane offsets ----
    const int swz = (l15 & 7) << 4;
    const int kb0 = (l4 * 16) ^ swz;                     // kk1 via ^64 (bit-disjoint)
    const int aRd = (wr * 128 + l15) * 128 + kb0;        // + s*32768 + f*2048
    const int bRd = 65536 + (wc * 64 + l15) * 128 + kb0; // + s*32768 + n*2048

    f32x4 acc[8][4];
#pragma unroll
    for (int f = 0; f < 8; ++f)
#pragma unroll
        for (int n = 0; n < 4; ++n)
            acc[f][n] = (f32x4){0.f, 0.f, 0.f, 0.f};

    short8 af_cur[4], af_nxt[4], bf_cur[4], bf_nxt[4];

    // ---- prologue: stage T0 (A+B) + T1-A; drain; read T0 g0 frags ----
#pragma unroll
    for (int r = 0; r < 4; ++r) stA(0, 0, r);
#pragma unroll
    for (int r = 0; r < 4; ++r) stB(0, 0, r);
#pragma unroll
    for (int r = 0; r < 4; ++r) stA(1, 64, r);
    __syncthreads();
#pragma unroll
    for (int f = 0; f < 4; ++f) af_cur[f] = *(const short8*)(lds + aRd + f * 2048);
#pragma unroll
    for (int n = 0; n < 4; ++n) bf_cur[n] = *(const short8*)(lds + bRd + n * 2048);

    const int NK = HID / BK; // 16
    for (int kt = 0; kt < NK; ++kt) {
        const int s = kt & 1, s1 = s ^ 1;
        const int aB = s * 32768 + aRd;
        const int bB = s * 32768 + bRd;

        // ---- g0: stage B(kt+1); read f4-7/kk0 + B/kk1; MFMA f0-3 x kk0 ----
        if (kt < NK - 1) {
#pragma unroll
            for (int r = 0; r < 4; ++r) stB(s1, (kt + 1) * BK, r);
        }
#pragma unroll
        for (int f = 0; f < 4; ++f) af_nxt[f] = *(const short8*)(lds + aB + (f + 4) * 2048);
#pragma unroll
        for (int n = 0; n < 4; ++n) bf_nxt[n] = *(const short8*)(lds + ((bB + n * 2048) ^ 64));
        __builtin_amdgcn_s_setprio(1);
#pragma unroll
        for (int f = 0; f < 4; ++f)
#pragma unroll
            for (int n = 0; n < 4; ++n)
                acc[f][n] = __builtin_amdgcn_mfma_f32_16x16x32_bf16(af_cur[f], bf_cur[n], acc[f][n], 0, 0, 0);
        __builtin_amdgcn_s_setprio(0);

        // ---- g1: read f0-3/kk1; MFMA f4-7 x kk0 ----
#pragma unroll
        for (int f = 0; f < 4; ++f) af_cur[f] = *(const short8*)(lds + ((aB + f * 2048) ^ 64));
        __builtin_amdgcn_s_setprio(1);
#pragma unroll
        for (int f = 0; f < 4; ++f)
#pragma unroll
            for (int n = 0; n < 4; ++n)
                acc[f + 4][n] = __builtin_amdgcn_mfma_f32_16x16x32_bf16(af_nxt[f], bf_cur[n], acc[f + 4][n], 0, 0, 0);
        __builtin_amdgcn_s_setprio(0);

        // ---- g2: read f4-7/kk1; MFMA f0-3 x kk1; barrier (vm+lgkm drain) ----
#pragma unroll
        for (int f = 0; f < 4; ++f) af_nxt[f] = *(const short8*)(lds + ((aB + (f + 4) * 2048) ^ 64));
        __builtin_amdgcn_s_setprio(1);
#pragma unroll
        for (int f = 0; f < 4; ++f)
#pragma unroll
            for (int n = 0; n < 4; ++n)
                acc[f][n] = __builtin_amdgcn_mfma_f32_16x16x32_bf16(af_cur[f], bf_nxt[n], acc[f][n], 0, 0, 0);
        __builtin_amdgcn_s_setprio(0);
        __syncthreads();   // drains vmcnt(0)+lgkmcnt(0): next slot staged, this slot's reads done

        // ---- g3: stage A(kt+2) into freed slot; read kt+1 g0 frags; MFMA f4-7 x kk1 ----
        if (kt < NK - 2) {
#pragma unroll
            for (int r = 0; r < 4; ++r) stA(s, (kt + 2) * BK, r);
        }
        if (kt < NK - 1) {
#pragma unroll
            for (int f = 0; f < 4; ++f) af_cur[f] = *(const short8*)(lds + s1 * 32768 + aRd + f * 2048);
#pragma unroll
            for (int n = 0; n < 4; ++n) bf_cur[n] = *(const short8*)(lds + s1 * 32768 + bRd + n * 2048);
        }
        __builtin_amdgcn_s_setprio(1);
#pragma unroll
        for (int f = 0; f < 4; ++f)
#pragma unroll
            for (int n = 0; n < 4; ++n)
                acc[f + 4][n] = __builtin_amdgcn_mfma_f32_16x16x32_bf16(af_nxt[f], bf_nxt[n], acc[f + 4][n], 0, 0, 0);
        __builtin_amdgcn_s_setprio(0);
    }

    // ---------------- epilogue: fused LSTM pointwise update ----------------
    float4* c4 = (float4*)cst + (size_t)bid * 4096;   // [f][tid] float4
    float4 cv[8];
#pragma unroll
    for (int f = 0; f < 8; ++f) cv[f] = c4[f * 512 + tid];

    const int hcg = by * 64 + wc * 16 + l15;          // global h column
    float wi0[4], wi1[4], bs_[4];
#pragma unroll
    for (int n = 0; n < 4; ++n) {
        int j = n * HID + hcg;
        wi0[n] = Wih[j * 2 + 0];
        wi1[n] = Wih[j * 2 + 1];
        bs_[n] = bih[j] + bhh[j];
    }
    const float2* xt2 = (const float2*)xt;
#pragma unroll
    for (int f = 0; f < 8; ++f) {
#pragma unroll
        for (int r = 0; r < 4; ++r) {
            int nrow = m0 + wr * 128 + f * 16 + l4 * 4 + r;
            float2 x = xt2[nrow];
            float gi = acc[f][0][r] + x.x * wi0[0] + x.y * wi1[0] + bs_[0];
            float gf = acc[f][1][r] + x.x * wi0[1] + x.y * wi1[1] + bs_[1];
            float gg = acc[f][2][r] + x.x * wi0[2] + x.y * wi1[2] + bs_[2];
            float go = acc[f][3][r] + x.x * wi0[3] + x.y * wi1[3] + bs_[3];
            float iv = sigf(gi), fv = sigf(gf);
            float gv = tanh_(gg), ov = sigf(go);
            float cn = fv * cv[f][r] + iv * gv;
            cv[f][r] = cn;
            hout[(size_t)nrow * HID + hcg] = f2bf(ov * tanh_(cn));
        }
        c4[f * 512 + tid] = cv[f];
    }
}

// ----------------------------------------------------------- out proj ----
__global__ __launch_bounds__(256) void out_proj_kernel(
    const ushort* __restrict__ h, const float* __restrict__ Wout,
    const float* __restrict__ bout, float* __restrict__ outt)
{
    const int wid = threadIdx.x >> 6, lane = threadIdx.x & 63;
    const int row = blockIdx.x * 4 + wid;
    const ushort* hr = h + (size_t)row * HID + lane * 16;
    float a0 = 0.f, a1 = 0.f;
#pragma unroll
    for (int half = 0; half < 2; ++half) {
        short8 hv = *(const short8*)(hr + half * 8);
#pragma unroll
        for (int j = 0; j < 8; ++j) {
            int k = lane * 16 + half * 8 + j;
            float f = bf2f((unsigned short)hv[j]);
            a0 += f * Wout[k];
            a1 += f * Wout[HID + k];
        }
    }
#pragma unroll
    for (int off = 32; off > 0; off >>= 1) {
        a0 += __shfl_down(a0, off);
        a1 += __shfl_down(a1, off);
    }
    if (lane == 0) {
        outt[row * 2 + 0] = a0 + bout[0];
        outt[row * 2 + 1] = a1 + bout[1];
    }
}

// ------------------------------------------------------------- launch ----
extern "C" void kernel_launch(void* const* d_in, const int* in_sizes, int n_in,
                              void* d_out, int out_size, void* d_ws, size_t ws_size,
                              hipStream_t stream) {
    const float* obs  = (const float*)d_in[0];
    const float* h0   = (const float*)d_in[1];
    const float* Wih  = (const float*)d_in[2];
    const float* Whh  = (const float*)d_in[3];
    const float* bih  = (const float*)d_in[4];
    const float* bhh  = (const float*)d_in[5];
    const float* Wout = (const float*)d_in[6];
    const float* bout = (const float*)d_in[7];
    float* out = (float*)d_out;

    char* ws = (char*)d_ws;
    ushort* Wg = (ushort*)(ws);                 // 8 MB bf16 W_hh (permuted)
    ushort* hA = (ushort*)(ws + (8  << 20));    // 8 MB bf16 h ping
    ushort* hB = (ushort*)(ws + (16 << 20));    // 8 MB bf16 h pong
    float*  c  = (float* )(ws + (24 << 20));    // 16 MB fp32 c state (block-local)

    prep_kernel<<<4096, 256, 0, stream>>>((const float4*)Whh, (const float4*)h0,
                                          (ushort4*)Wg, (ushort4*)hA, (float4*)c,
                                          N_BATCH * HID / 4);

    ushort* hin = hA;
    ushort* hou = hB;
    for (int t = 0; t < OBSLEN; ++t) {
        const float* xt = obs + (size_t)(t == 0 ? 0 : (t - 1)) * N_BATCH * 2;
        lstm_step_kernel<<<dim3(N_BATCH / BM, (4 * HID) / 256), 512, 0, stream>>>(
            hin, Wg, xt, Wih, bih, bhh, c, hou);
        out_proj_kernel<<<N_BATCH / 4, 256, 0, stream>>>(
            hou, Wout, bout, out + (size_t)t * N_BATCH * 2);
        ushort* tmp = hin; hin = hou; hou = tmp;
    }
}